// Round 14
// baseline (139.417 us; speedup 1.0000x reference)
//
#include <hip/hip_runtime.h>

typedef short short8 __attribute__((ext_vector_type(8)));
typedef float f32x4 __attribute__((ext_vector_type(4)));

#define QSCALE 0.18033688011112042f  // 0.125 * log2(e), folded into Wq/bq

__device__ __forceinline__ unsigned short f2bf(float f) {
  unsigned u = __builtin_bit_cast(unsigned, f);
  u += 0x7fffu + ((u >> 16) & 1u);
  return (unsigned short)(u >> 16);
}

__device__ __forceinline__ void gload16(const void* g, void* l) {
  typedef __attribute__((address_space(1))) unsigned int gas;
  typedef __attribute__((address_space(3))) unsigned int las;
  __builtin_amdgcn_global_load_lds((gas*)(unsigned long long)g,
                                   (las*)(unsigned)(unsigned long long)l, 16, 0, 0);
}

__device__ __forceinline__ short8 mk8(unsigned r0, unsigned r1, unsigned r2, unsigned r3) {
  union { unsigned u[4]; short8 s; } t;
  t.u[0] = r0; t.u[1] = r1; t.u[2] = r2; t.u[3] = r3;
  return t.s;
}

#define MFMA16(a, b, c) __builtin_amdgcn_mfma_f32_16x16x32_bf16(a, b, c, 0, 0, 0)

// ---------------------------------------------------------------- weights ----
// W fp32 [k][n] -> Wt bf16 [n][k]; Wq additionally pre-scaled by QSCALE.
__global__ __launch_bounds__(256) void wtrans_kernel(
    const float* __restrict__ Wq, const float* __restrict__ Wk,
    const float* __restrict__ Wv, const float* __restrict__ Wo,
    unsigned short* __restrict__ Wt) {
  const int wsel = blockIdx.z;
  const float* W = wsel == 0 ? Wq : wsel == 1 ? Wk : wsel == 2 ? Wv : Wo;
  const float wscale = (wsel == 0) ? QSCALE : 1.0f;
  unsigned short* out = Wt + (long)wsel * 1048576;
  __shared__ float lds[64][65];
  const int t = threadIdx.x;
  const int k0 = blockIdx.x * 64, n0 = blockIdx.y * 64;
#pragma unroll
  for (int i = 0; i < 4; ++i) {
    int r = (t >> 4) + i * 16, c4 = (t & 15) * 4;
    float4 vv = *(const float4*)(W + (long)(k0 + r) * 1024 + n0 + c4);
    lds[r][c4] = vv.x; lds[r][c4 + 1] = vv.y; lds[r][c4 + 2] = vv.z; lds[r][c4 + 3] = vv.w;
  }
  __syncthreads();
#pragma unroll
  for (int i = 0; i < 16; ++i) {
    int flat = t + i * 256;
    int n = flat >> 6, kk = flat & 63;
    out[(long)(n0 + n) * 1024 + k0 + kk] = f2bf(lds[kk][n] * wscale);
  }
}

// ---------------------------------------------------------------- mask pack --
__global__ __launch_bounds__(256) void maskpack_kernel(const int* __restrict__ mask,
                                                       unsigned* __restrict__ bits) {
  const long n = 8388608;  // 2*2048*2048
  const long stride = (long)gridDim.x * 256;
  const int lane = threadIdx.x & 63;
  for (long i = (long)blockIdx.x * 256 + threadIdx.x; i < n; i += stride) {
    unsigned long long bal = __ballot(mask[i] != 0);
    if ((lane & 31) == 0) bits[i >> 5] = (unsigned)(bal >> (lane & 32));
  }
}

// ---------------------------------------------------------------- layernorm --
__global__ __launch_bounds__(256) void ln_kernel(
    const float* __restrict__ q, const float* __restrict__ k, const float* __restrict__ v,
    const float* __restrict__ gamma, const float* __restrict__ beta,
    unsigned short* __restrict__ lnq, unsigned short* __restrict__ lnk,
    unsigned short* __restrict__ lnv) {
  const int row = blockIdx.x, which = blockIdx.y;
  const float* x = (which == 0 ? q : which == 1 ? k : v) + (long)row * 1024;
  unsigned short* y = (which == 0 ? lnq : which == 1 ? lnk : lnv) + (long)row * 1024;
  const int t = threadIdx.x, lane = t & 63, wv = t >> 6;
  float4 xv = ((const float4*)x)[t];
  float s = xv.x + xv.y + xv.z + xv.w;
  float s2 = xv.x * xv.x + xv.y * xv.y + xv.z * xv.z + xv.w * xv.w;
#pragma unroll
  for (int off = 32; off > 0; off >>= 1) {
    s += __shfl_down(s, off);
    s2 += __shfl_down(s2, off);
  }
  __shared__ float red[8];
  if (lane == 0) { red[wv] = s; red[wv + 4] = s2; }
  __syncthreads();
  float tot = red[0] + red[1] + red[2] + red[3];
  float tot2 = red[4] + red[5] + red[6] + red[7];
  float mu = tot * (1.0f / 1024.0f);
  float var = tot2 * (1.0f / 1024.0f) - mu * mu;
  float rs = rsqrtf(var + 1e-5f);
  float4 g = ((const float4*)gamma)[t];
  float4 be = ((const float4*)beta)[t];
  ushort4 o;
  o.x = f2bf((xv.x - mu) * rs * g.x + be.x);
  o.y = f2bf((xv.y - mu) * rs * g.y + be.y);
  o.z = f2bf((xv.z - mu) * rs * g.z + be.z);
  o.w = f2bf((xv.w - mu) * rs * g.w + be.w);
  ((ushort4*)y)[t] = o;
}

// ---------------------------------------------------------------- GEMM -------
// Triple-buffered counted-vmcnt K-loop (T3/T4): BK=32, stage(kt+2) issued each
// iter, end-of-iter wait vmcnt(stage_loads) = "previous stage done, newest in
// flight" (never drains to 0 mid-loop). One barrier + one counted wait per iter.
// 64B LDS rows swizzled part = g ^ ((row>>1)&3), inverse perm on gload source.
// MODE 0: bf16 out, heads layout [B,H,S,64]; z==2 writes V^T [BH][64][S] to outV
// with kv-slot permutation (pos = (s&~31)|((s>>2)&3)<<3|((s>>4)&1)<<2) so the
// attention's PV A-fragment is lane-local. MODE 1: fp32 out row-major.
template <int BM, int MODE>
__global__ __launch_bounds__(256) void gemm_kernel(
    const unsigned short* __restrict__ A0, const unsigned short* __restrict__ A1,
    const unsigned short* __restrict__ A2, const unsigned short* __restrict__ Wt,
    const float* __restrict__ b0, const float* __restrict__ b1,
    const float* __restrict__ b2, unsigned short* __restrict__ outB,
    unsigned short* __restrict__ outV, float* __restrict__ outF) {
  constexpr int MI = BM / 32;
  constexpr int NT = 32;           // K=1024 / BK=32
  constexpr int ACHA = BM / 64;    // A 16B-chunks per thread per stage
  constexpr int ABUF = BM * 64;    // bytes per A buffer
  const int z = blockIdx.z;
  const unsigned short* A = z == 0 ? A0 : z == 1 ? A1 : A2;
  const unsigned short* Bt = Wt + (long)z * 1048576;
  const float* bias = z == 0 ? b0 : z == 1 ? b1 : b2;
  unsigned short* outz = outB + (long)z * 4194304;
  const float bscale = (MODE == 0 && z == 0) ? QSCALE : 1.0f;

  __shared__ char lds[3 * (BM * 64) + 24576];  // A bufs x3 | B bufs x3 (8KB each)
  char* As = lds;
  char* Bs = lds + 3 * ABUF;
  const int tid = threadIdx.x, lane = tid & 63, w = tid >> 6;
  const int g = lane >> 4;
  const int wr = w >> 1, wc = w & 1;
  const int m0 = blockIdx.x * BM, n0 = blockIdx.y * 128;

  f32x4 acc[MI][4] = {};

#define GSTAGE(KT, BUF)                                                       \
  {                                                                           \
    _Pragma("unroll") for (int i = 0; i < ACHA; ++i) {                        \
      int cc = tid + i * 256;                                                 \
      int row = cc >> 2, p = cc & 3;                                          \
      int kk = p ^ ((row >> 1) & 3);                                          \
      gload16(A + (long)(m0 + row) * 1024 + (KT)*32 + kk * 8,                 \
              As + (BUF)*ABUF + cc * 16);                                     \
    }                                                                         \
    _Pragma("unroll") for (int i = 0; i < 2; ++i) {                           \
      int cc = tid + i * 256;                                                 \
      int row = cc >> 2, p = cc & 3;                                          \
      int kk = p ^ ((row >> 1) & 3);                                          \
      gload16(Bt + (long)(n0 + row) * 1024 + (KT)*32 + kk * 8,                \
              Bs + (BUF)*8192 + cc * 16);                                     \
    }                                                                         \
  }

#define WAIT_STAGE                                                            \
  if constexpr (BM == 128) {                                                  \
    asm volatile("s_waitcnt vmcnt(4)" ::: "memory");                          \
  } else {                                                                    \
    asm volatile("s_waitcnt vmcnt(3)" ::: "memory");                          \
  }

  GSTAGE(0, 0);
  GSTAGE(1, 1);
  WAIT_STAGE;  // stage 0 complete, stage 1 in flight
  __builtin_amdgcn_s_barrier();

  int cur = 0;
  for (int kt = 0; kt < NT; ++kt) {
    int sb = cur + 2;
    if (sb >= 3) sb -= 3;
    if (kt + 2 < NT) GSTAGE(kt + 2, sb);

    short8 af[MI], bf[4];
#pragma unroll
    for (int mi = 0; mi < MI; ++mi) {
      int row = wr * (BM / 2) + mi * 16 + (lane & 15);
      int part = g ^ ((row >> 1) & 3);
      af[mi] = *(const short8*)(As + cur * ABUF + row * 64 + part * 16);
    }
#pragma unroll
    for (int ni = 0; ni < 4; ++ni) {
      int row = wc * 64 + ni * 16 + (lane & 15);
      int part = g ^ ((row >> 1) & 3);
      bf[ni] = *(const short8*)(Bs + cur * 8192 + row * 64 + part * 16);
    }
    __builtin_amdgcn_s_setprio(1);
#pragma unroll
    for (int mi = 0; mi < MI; ++mi)
#pragma unroll
      for (int ni = 0; ni < 4; ++ni)
        acc[mi][ni] = MFMA16(af[mi], bf[ni], acc[mi][ni]);
    __builtin_amdgcn_s_setprio(0);

    asm volatile("s_waitcnt lgkmcnt(0)" ::: "memory");
    if (kt + 2 < NT) {
      WAIT_STAGE;  // stage kt+1 complete, kt+2 in flight
    } else if (kt + 1 < NT) {
      asm volatile("s_waitcnt vmcnt(0)" ::: "memory");  // drain final stage
    }
    __builtin_amdgcn_s_barrier();
    cur = (cur + 1 == 3) ? 0 : cur + 1;
  }
#undef WAIT_STAGE
#undef GSTAGE

#pragma unroll
  for (int mi = 0; mi < MI; ++mi) {
    int mbase = m0 + wr * (BM / 2) + mi * 16 + ((lane >> 4) << 2);
#pragma unroll
    for (int ni = 0; ni < 4; ++ni) {
      int j = n0 + wc * 64 + ni * 16 + (lane & 15);
      float bj = bias[j] * bscale;
      float t0 = acc[mi][ni][0] + bj;
      float t1 = acc[mi][ni][1] + bj;
      float t2 = acc[mi][ni][2] + bj;
      float t3 = acc[mi][ni][3] + bj;
      if constexpr (MODE == 0) {
        int b = mbase >> 11, s = mbase & 2047;
        int h = j >> 6, d = j & 63;
        if (z == 2) {
          unsigned lo, hi;
          asm("v_cvt_pk_bf16_f32 %0, %1, %2" : "=v"(lo) : "v"(t0), "v"(t1));
          asm("v_cvt_pk_bf16_f32 %0, %1, %2" : "=v"(hi) : "v"(t2), "v"(t3));
          uint2 o; o.x = lo; o.y = hi;
          // kv-slot permutation (s is 4-aligned; 4-run stays contiguous)
          int sp = (s & ~31) | (((s >> 2) & 3) << 3) | (((s >> 4) & 1) << 2);
          *(uint2*)(outV + ((long)(b * 16 + h) * 64 + d) * 2048 + sp) = o;
        } else {
          long base = (((long)(b * 16 + h)) * 2048 + s) * 64 + d;
          outz[base] = f2bf(t0);
          outz[base + 64] = f2bf(t1);
          outz[base + 128] = f2bf(t2);
          outz[base + 192] = f2bf(t3);
        }
      } else {
        outF[(long)mbase * 1024 + j] = t0;
        outF[(long)(mbase + 1) * 1024 + j] = t1;
        outF[(long)(mbase + 2) * 1024 + j] = t2;
        outF[(long)(mbase + 3) * 1024 + j] = t3;
      }
    }
  }
}

// ---------------------------------------------------------------- attention --
// R12 (62 us): swapped-QK^T, fixed-max softmax, P fully in registers (permuted
// V^T upstream), K+V LDS dbuf, 32 q/wave (2 q-groups), 4-wave blocks, grid 512,
// phase-staggered tile order. FROZEN this round.
__global__ __launch_bounds__(256, 2) void attn_kernel(
    const unsigned short* __restrict__ qh, const unsigned short* __restrict__ kh,
    const unsigned short* __restrict__ vt, const unsigned* __restrict__ mbits,
    unsigned short* __restrict__ O) {
  constexpr int S = 2048, NT = 32;
  __shared__ char lds[32768];  // K dbuf 2x8K | V dbuf 2x8K
  char* Ks = lds;
  char* Vts = lds + 16384;
  const int tid = threadIdx.x, lane = tid & 63, w = tid >> 6;
  const int g = lane >> 4, c = lane & 15;

  // XCD-bijective swizzle: 512 blocks -> 64 consecutive per XCD
  const int flat = blockIdx.y * 16 + blockIdx.x;
  const int fl2 = (flat & 7) * 64 + (flat >> 3);
  const int qb = fl2 & 15, bh = fl2 >> 4, b = bh >> 4;
  const int kt0 = (fl2 & 3) * 8;  // phase stagger across co-resident blocks

  const unsigned short* qp = qh + (long)bh * S * 64;
  const unsigned short* kp = kh + (long)bh * S * 64;
  const unsigned short* vp = vt + (long)bh * 64 * S;
  unsigned short* op = O + (long)bh * S * 64;
  const unsigned* mrow = mbits + (long)b * S * 64;
  const int q0 = qb * 128 + w * 32;
  const int myq0 = q0 + c, myq1 = q0 + 16 + c;

  // Q as B-frags (pre-scaled by QSCALE upstream), 2 q-groups
  short8 bq_[2][2];
#pragma unroll
  for (int qg = 0; qg < 2; ++qg)
#pragma unroll
    for (int ds = 0; ds < 2; ++ds)
      bq_[qg][ds] = *(const short8*)(qp + (long)(q0 + qg * 16 + c) * 64 + ds * 32 + g * 8);

  f32x4 o_acc[2][4] = {};
  float lp0 = 0.f, lp1 = 0.f;

#define STAGE(KT, BUF)                                                              \
  {                                                                                 \
    _Pragma("unroll") for (int i = 0; i < 2; ++i) {                                 \
      int cc = tid + i * 256;                                                       \
      int row = cc >> 3, pg = (cc & 7) ^ (row & 7);                                 \
      gload16(kp + (long)((KT)*64 + row) * 64 + pg * 8, Ks + (BUF)*8192 + cc * 16); \
    }                                                                               \
    _Pragma("unroll") for (int i = 0; i < 2; ++i) {                                 \
      int cc = tid + i * 256;                                                       \
      int row = cc >> 3, pg = (cc & 7) ^ (row & 7);                                 \
      gload16(vp + (long)row * S + (KT)*64 + pg * 8, Vts + (BUF)*8192 + cc * 16);   \
    }                                                                               \
  }

  // softmax (fixed-max, pre-scaled) for one q-group -> PA registers
#define SOFTMAX(SC, MC, LP, PA0, PA1)                                               \
  {                                                                                 \
    unsigned ws0 = MC.x >> (g * 4), ws1 = MC.y >> (g * 4);                          \
    unsigned pw[8];                                                                 \
    _Pragma("unroll") for (int kf = 0; kf < 4; ++kf) {                              \
      unsigned wsh = ((kf >= 2) ? ws1 : ws0) >> ((kf & 1) * 16);                    \
      float pv0 = __builtin_amdgcn_exp2f(SC[kf][0]);                                \
      float pv1 = __builtin_amdgcn_exp2f(SC[kf][1]);                                \
      float pv2 = __builtin_amdgcn_exp2f(SC[kf][2]);                                \
      float pv3 = __builtin_amdgcn_exp2f(SC[kf][3]);                                \
      pv0 = (wsh & 1u) ? pv0 : 0.f;                                                 \
      pv1 = (wsh & 2u) ? pv1 : 0.f;                                                 \
      pv2 = (wsh & 4u) ? pv2 : 0.f;                                                 \
      pv3 = (wsh & 8u) ? pv3 : 0.f;                                                 \
      LP += (pv0 + pv1) + (pv2 + pv3);                                              \
      asm("v_cvt_pk_bf16_f32 %0, %1, %2" : "=v"(pw[kf * 2]) : "v"(pv0), "v"(pv1));  \
      asm("v_cvt_pk_bf16_f32 %0, %1, %2" : "=v"(pw[kf * 2 + 1]) : "v"(pv2), "v"(pv3)); \
    }                                                                               \
    PA0 = mk8(pw[0], pw[1], pw[2], pw[3]);                                          \
    PA1 = mk8(pw[4], pw[5], pw[6], pw[7]);                                          \
  }

  STAGE(kt0, 0);
  uint2 m0c = *(const uint2*)(mrow + (long)myq0 * 64 + kt0 * 2);
  uint2 m1c = *(const uint2*)(mrow + (long)myq1 * 64 + kt0 * 2);
  uint2 m0n, m1n;

  for (int kt = 0; kt < NT; ++kt) {
    const int cur = kt & 1;
    if (kt + 1 < NT) {
      const int nx = (kt0 + kt + 1) & 31;
      STAGE(nx, cur ^ 1);
      m0n = *(const uint2*)(mrow + (long)myq0 * 64 + nx * 2);
      m1n = *(const uint2*)(mrow + (long)myq1 * 64 + nx * 2);
      // 6 loads issued this iter (4 stage + 2 masks); drain the previous 6.
      asm volatile("s_waitcnt vmcnt(6)" ::: "memory");
    } else {
      asm volatile("s_waitcnt vmcnt(0)" ::: "memory");
    }
    __builtin_amdgcn_s_barrier();

    // QK^T (swapped): each K-frag read feeds both q-groups
    f32x4 sc0[4] = {}, sc1[4] = {};
    const char* Kb = Ks + cur * 8192;
    __builtin_amdgcn_s_setprio(1);
#pragma unroll
    for (int ds = 0; ds < 2; ++ds) {
#pragma unroll
      for (int kf = 0; kf < 4; ++kf) {
        int row = kf * 16 + c;
        int part = (ds * 4 + g) ^ (row & 7);
        short8 ak = *(const short8*)(Kb + row * 128 + part * 16);
        sc0[kf] = MFMA16(ak, bq_[0][ds], sc0[kf]);
        sc1[kf] = MFMA16(ak, bq_[1][ds], sc1[kf]);
      }
    }
    __builtin_amdgcn_s_setprio(0);

    short8 pa00, pa01, pa10, pa11;
    SOFTMAX(sc0, m0c, lp0, pa00, pa01);
    SOFTMAX(sc1, m1c, lp1, pa10, pa11);
    m0c = m0n;
    m1c = m1n;

    // PV: each V-frag read feeds both q-groups
    const char* Vb = Vts + cur * 8192;
    __builtin_amdgcn_s_setprio(1);
#pragma unroll
    for (int ks = 0; ks < 2; ++ks) {
      short8 paA = ks ? pa01 : pa00;
      short8 paB = ks ? pa11 : pa10;
      int part = ks * 4 + g;
#pragma unroll
      for (int nd = 0; nd < 4; ++nd) {
        int d = nd * 16 + c;
        short8 bv = *(const short8*)(Vb + d * 128 + ((part ^ (d & 7)) * 16));
        o_acc[0][nd] = MFMA16(paA, bv, o_acc[0][nd]);
        o_acc[1][nd] = MFMA16(paB, bv, o_acc[1][nd]);
      }
    }
    __builtin_amdgcn_s_setprio(0);

    // drain LDS reads before barrier so next stage can't overwrite in-flight
    asm volatile("s_waitcnt lgkmcnt(0)" ::: "memory");
    __builtin_amdgcn_sched_barrier(0);
    __builtin_amdgcn_s_barrier();
  }
#undef SOFTMAX
#undef STAGE

  // epilogue: reduce l across the 4 g-groups, divide, store (both q-groups)
  lp0 += __shfl_xor(lp0, 16);
  lp0 += __shfl_xor(lp0, 32);
  lp1 += __shfl_xor(lp1, 16);
  lp1 += __shfl_xor(lp1, 32);
#pragma unroll
  for (int r = 0; r < 4; ++r) {
    float lr0 = __shfl(lp0, g * 4 + r);
    float lr1 = __shfl(lp1, g * 4 + r);
    float inv0 = 1.0f / lr0;
    float inv1 = 1.0f / lr1;
    int qrow0 = q0 + g * 4 + r;
    int qrow1 = q0 + 16 + g * 4 + r;
#pragma unroll
    for (int nd = 0; nd < 4; ++nd) {
      op[(long)qrow0 * 64 + nd * 16 + c] = f2bf(o_acc[0][nd][r] * inv0);
      op[(long)qrow1 * 64 + nd * 16 + c] = f2bf(o_acc[1][nd][r] * inv1);
    }
  }
}

// ---------------------------------------------------------------- launch -----
extern "C" void kernel_launch(void* const* d_in, const int* in_sizes, int n_in,
                              void* d_out, int out_size, void* d_ws, size_t ws_size,
                              hipStream_t stream) {
  const float* q = (const float*)d_in[0];
  const float* k = (const float*)d_in[1];
  const float* v = (const float*)d_in[2];
  const int* mask = (const int*)d_in[3];
  const float* Wq = (const float*)d_in[4];
  const float* bq = (const float*)d_in[5];
  const float* Wk = (const float*)d_in[6];
  const float* bk = (const float*)d_in[7];
  const float* Wv = (const float*)d_in[8];
  const float* bv = (const float*)d_in[9];
  const float* Wo = (const float*)d_in[10];
  const float* bo = (const float*)d_in[11];
  const float* gamma = (const float*)d_in[12];
  const float* beta = (const float*)d_in[13];
  float* out = (float*)d_out;

  char* ws = (char*)d_ws;
  unsigned short* Wt = (unsigned short*)ws;                         // 8 MB
  unsigned* mbits = (unsigned*)(ws + 8u * 1024 * 1024);             // 1 MB
  unsigned short* lnq = (unsigned short*)(ws + 9u * 1024 * 1024);   // 8 MB
  unsigned short* lnk = lnq + 4194304;
  unsigned short* lnv = lnk + 4194304;
  unsigned short* qh = lnv + 4194304;
  unsigned short* kh = qh + 4194304;
  unsigned short* vtb = kh + 4194304;  // permuted V^T written by QKV GEMM (z==2)
  unsigned short* Ob = lnq;            // alias: lnq dead after QKV GEMM

  wtrans_kernel<<<dim3(16, 16, 4), 256, 0, stream>>>(Wq, Wk, Wv, Wo, Wt);
  maskpack_kernel<<<1024, 256, 0, stream>>>(mask, mbits);
  ln_kernel<<<dim3(4096, 3), 256, 0, stream>>>(q, k, v, gamma, beta, lnq, lnk, lnv);
  gemm_kernel<128, 0><<<dim3(32, 8, 3), 256, 0, stream>>>(lnq, lnk, lnv, Wt, bq, bk, bv,
                                                          qh, vtb, nullptr);
  attn_kernel<<<dim3(16, 32), 256, 0, stream>>>(qh, kh, vtb, mbits, Ob);
  gemm_kernel<64, 1><<<dim3(64, 8, 1), 256, 0, stream>>>(Ob, Ob, Ob, Wt + 3 * 1048576,
                                                         bo, bo, bo, nullptr, nullptr, out);
}